// Round 9
// baseline (180.857 us; speedup 1.0000x reference)
//
#include <hip/hip_runtime.h>
#include <cstdint>

#define EMBD 1024
#define NH 16
#define DH 64
#define BB 2
#define SS 2048
#define M_TOT (BB*SS)     // 4096
#define N_QKV (3*EMBD)    // 3072

typedef __bf16 bf16_t;
typedef bf16_t bf16x8 __attribute__((ext_vector_type(8)));
typedef float f32x4 __attribute__((ext_vector_type(4)));
typedef unsigned short u16;
typedef unsigned int u32;

static __device__ __forceinline__ u16 f2bf(float f) {
    union { float f; unsigned u; } c; c.f = f;
    unsigned u = c.u;
    unsigned r = (u + 0x7FFFu + ((u >> 16) & 1u)) >> 16;  // RNE
    return (u16)r;
}

// async global->LDS, 16B per lane; LDS dest must be wave-uniform base + lane*16
#define GLDS16(gp, lp) \
    __builtin_amdgcn_global_load_lds((const __attribute__((address_space(1))) void*)(gp), \
                                     (__attribute__((address_space(3))) void*)(lp), 16, 0, 0)

// ---------------- fused cast fp32 -> bf16 for x, W_in, W_out ----------------
#define NX8 (M_TOT * EMBD / 8)          // 524288
#define NWI8 (N_QKV * EMBD / 8)         // 393216
#define NWO8 (EMBD * EMBD / 8)          // 131072
__global__ void cast_all(const float* __restrict__ x, const float* __restrict__ wi,
                         const float* __restrict__ wo, u16* __restrict__ xb,
                         u16* __restrict__ wib, u16* __restrict__ wob) {
    int i = blockIdx.x * blockDim.x + threadIdx.x;
    const float* s; u16* d; int off;
    if (i < NX8)              { s = x;  d = xb;  off = i; }
    else if (i < NX8 + NWI8)  { s = wi; d = wib; off = i - NX8; }
    else                      { s = wo; d = wob; off = i - NX8 - NWI8; }
    const float4* s4 = (const float4*)s;
    float4 a = s4[2 * off];
    float4 b = s4[2 * off + 1];
    union { u16 u[8]; uint4 v; } r;
    r.u[0] = f2bf(a.x); r.u[1] = f2bf(a.y); r.u[2] = f2bf(a.z); r.u[3] = f2bf(a.w);
    r.u[4] = f2bf(b.x); r.u[5] = f2bf(b.y); r.u[6] = f2bf(b.z); r.u[7] = f2bf(b.w);
    ((uint4*)d)[off] = r.v;
}

// ---------------- QKV GEMM: dbuf DMA pipeline, 1 barrier/iter ---------------
// C[i][o] = sum_d x[i][d]*W_in[o][d] + b_in[o]
// Epilogue layouts:
//   Q  [B,H,S,64] row-major, scaled by 0.125*log2(e)
//   Kf fragment-linear: per head, per 16-key tile (1024 u16):
//        off = tile*1024 + (d>>5)*512 + (key&15)*32 + ((d>>3)&3)*8 + (d&7)
//   Vpf fragment-linear, keys permuted per 32-block (2048 u16/group):
//        p = ((s>>2)&3)*8 + ((s>>4)&1)*4 + (s&3)
//        off = (s>>5)*2048 + (d>>4)*512 + (d&15)*32 + p
#define QSCALE (0.125f * 1.4426950408889634f)
__global__ __launch_bounds__(256) void gemm_qkv(
    const u16* __restrict__ Xb,   // [4096][1024]
    const u16* __restrict__ Wb,   // [3072][1024]
    const float* __restrict__ b_in,
    u16* __restrict__ Q, u16* __restrict__ Kf, u16* __restrict__ Vpf)
{
    __shared__ u16 AB[2][8192];   // [buf][A 4096 | B 4096]  32 KB
    const int t = threadIdx.x;
    const int lane = t & 63;
    const int wave = t >> 6;
    const int wm = wave >> 1, wn = wave & 1;
    const int quad = lane >> 4, l16 = lane & 15;
    const int m0 = blockIdx.y * 128, n0 = blockIdx.x * 128;

    const int s0i = t, s1i = 256 + t;
    const u16* ga0 = Xb + (size_t)(m0 + (s0i >> 2)) * EMBD + (s0i & 3) * 8;
    const u16* ga1 = Xb + (size_t)(m0 + (s1i >> 2)) * EMBD + (s1i & 3) * 8;
    const u16* gb0 = Wb + (size_t)(n0 + (s0i >> 2)) * EMBD + (s0i & 3) * 8;
    const u16* gb1 = Wb + (size_t)(n0 + (s1i >> 2)) * EMBD + (s1i & 3) * 8;

    f32x4 acc[4][4] = {};

    // prologue: DMA k-tile 0 into buf 0
    {
        u16* buf = &AB[0][0];
        GLDS16(ga0, buf + s0i * 8);
        GLDS16(ga1, buf + s1i * 8);
        GLDS16(gb0, buf + 4096 + s0i * 8);
        GLDS16(gb1, buf + 4096 + s1i * 8);
    }

    for (int it = 0; it < EMBD / 32; ++it) {
        // drain own DMAs (issued a full compute-phase ago), then barrier
        asm volatile("s_waitcnt vmcnt(0)" ::: "memory");
        __syncthreads();
        if (it + 1 < EMBD / 32) {
            int k0 = (it + 1) * 32;
            u16* buf = &AB[(it + 1) & 1][0];
            GLDS16(ga0 + k0, buf + s0i * 8);
            GLDS16(ga1 + k0, buf + s1i * 8);
            GLDS16(gb0 + k0, buf + 4096 + s0i * 8);
            GLDS16(gb1 + k0, buf + 4096 + s1i * 8);
        }
        const u16* As = &AB[it & 1][0];
        const u16* Bs = &AB[it & 1][4096];
        bf16x8 af[4], bfr[4];
#pragma unroll
        for (int im = 0; im < 4; ++im)
            af[im] = *(const bf16x8*)(As + (wm * 64 + im * 16 + l16) * 32 + quad * 8);
#pragma unroll
        for (int in = 0; in < 4; ++in)
            bfr[in] = *(const bf16x8*)(Bs + (wn * 64 + in * 16 + l16) * 32 + quad * 8);
#pragma unroll
        for (int im = 0; im < 4; ++im)
#pragma unroll
            for (int in = 0; in < 4; ++in)
                acc[im][in] = __builtin_amdgcn_mfma_f32_16x16x32_bf16(
                    af[im], bfr[in], acc[im][in], 0, 0, 0);
    }

    // epilogue: C/D layout col=lane&15, row=quad*4+reg
#pragma unroll
    for (int im = 0; im < 4; ++im) {
        int rbase = m0 + wm * 64 + im * 16 + quad * 4;
        int b = rbase >> 11, ss = rbase & (SS - 1);     // ss%4==0, keys ss..ss+3
#pragma unroll
        for (int in = 0; in < 4; ++in) {
            int col = n0 + wn * 64 + in * 16 + l16;
            float bias = b_in[col];
            float v0 = acc[im][in][0] + bias;
            float v1 = acc[im][in][1] + bias;
            float v2 = acc[im][in][2] + bias;
            float v3 = acc[im][in][3] + bias;
            if (col < EMBD) {
                int h = col >> 6, d = col & 63;
                u16* qp = Q + (((size_t)(b * NH + h) * SS) + ss) * DH + d;
                qp[0]      = f2bf(v0 * QSCALE);
                qp[DH]     = f2bf(v1 * QSCALE);
                qp[2 * DH] = f2bf(v2 * QSCALE);
                qp[3 * DH] = f2bf(v3 * QSCALE);
            } else if (col < 2 * EMBD) {
                int c = col - EMBD; int h = c >> 6, d = c & 63;
                u16* kp = Kf + (size_t)(b * NH + h) * SS * DH
                          + (ss >> 4) * 1024 + (d >> 5) * 512
                          + (ss & 15) * 32 + ((d >> 3) & 3) * 8 + (d & 7);
                kp[0]  = f2bf(v0);
                kp[32] = f2bf(v1);
                kp[64] = f2bf(v2);
                kp[96] = f2bf(v3);
            } else {
                int c = col - 2 * EMBD; int h = c >> 6, d = c & 63;
                int p32 = ((ss >> 2) & 3) * 8 + ((ss >> 4) & 1) * 4;  // + j for key ss+j
                u32 lo = (u32)f2bf(v0) | ((u32)f2bf(v1) << 16);
                u32 hi = (u32)f2bf(v2) | ((u32)f2bf(v3) << 16);
                uint2 pk; pk.x = lo; pk.y = hi;
                *(uint2*)(Vpf + (size_t)(b * NH + h) * SS * DH
                          + (ss >> 5) * 2048 + (d >> 4) * 512 + (d & 15) * 32 + p32) = pk;
            }
        }
    }
}

// ---------------- attention v7 (unchanged from R8): DMA dbuf, 1 barrier/iter
#define OST 72
__global__ __launch_bounds__(256, 2) void attn(
    const u16* __restrict__ Q, const u16* __restrict__ Kf,
    const u16* __restrict__ Vpf, u16* __restrict__ AO)
{
    __shared__ u16 KV[2][8192];     // [buf][K 4096 | V 4096]  32 KB
    const int t = threadIdx.x;
    const int lane = t & 63, w = t >> 6;
    const int quad = lane >> 4, l16 = lane & 15;
    const int b0 = blockIdx.x;
    const int bh = (b0 & 7) * 4 + ((b0 >> 3) & 3);   // XCD-clustered heads
    const int qt = b0 >> 5;
    const int q0 = qt * 128 + w * 32;

    const u16* Qh = Q + ((size_t)bh * SS + q0) * DH;
    const u16* Kh = Kf + (size_t)bh * SS * DH;     // chunk it: + it*4096
    const u16* Vh = Vpf + (size_t)bh * SS * DH;    // chunk it: + it*4096

    bf16x8 qb[2][2];
#pragma unroll
    for (int qi = 0; qi < 2; ++qi) {
        qb[qi][0] = *(const bf16x8*)(Qh + (qi * 16 + l16) * DH + quad * 8);
        qb[qi][1] = *(const bf16x8*)(Qh + (qi * 16 + l16) * DH + 32 + quad * 8);
    }

    f32x4 o[2][4] = {};
    float lsum[2] = {0.f, 0.f};

    GLDS16(Kh + t * 8,        &KV[0][0] + t * 8);
    GLDS16(Kh + 2048 + t * 8, &KV[0][0] + 2048 + t * 8);
    GLDS16(Vh + t * 8,        &KV[0][4096] + t * 8);
    GLDS16(Vh + 2048 + t * 8, &KV[0][4096] + 2048 + t * 8);

    for (int it = 0; it < SS / 64; ++it) {
        asm volatile("s_waitcnt vmcnt(0)" ::: "memory");
        __syncthreads();
        if (it + 1 < SS / 64) {
            const u16* kc = Kh + (it + 1) * 4096;
            const u16* vc = Vh + (it + 1) * 4096;
            u16* kb = &KV[(it + 1) & 1][0];
            u16* vb = &KV[(it + 1) & 1][4096];
            GLDS16(kc + t * 8,        kb + t * 8);
            GLDS16(kc + 2048 + t * 8, kb + 2048 + t * 8);
            GLDS16(vc + t * 8,        vb + t * 8);
            GLDS16(vc + 2048 + t * 8, vb + 2048 + t * 8);
        }
        const u16* Kb = &KV[it & 1][0];
        const u16* Vb = &KV[it & 1][4096];
#pragma unroll
        for (int g = 0; g < 2; ++g) {    // 2 groups of 32 keys
            bf16x8 ka00 = *(const bf16x8*)(Kb + (2 * g) * 1024 +       l16 * 32 + quad * 8);
            bf16x8 ka01 = *(const bf16x8*)(Kb + (2 * g) * 1024 + 512 + l16 * 32 + quad * 8);
            bf16x8 ka10 = *(const bf16x8*)(Kb + (2 * g + 1) * 1024 +       l16 * 32 + quad * 8);
            bf16x8 ka11 = *(const bf16x8*)(Kb + (2 * g + 1) * 1024 + 512 + l16 * 32 + quad * 8);
            bf16x8 va0 = *(const bf16x8*)(Vb + g * 2048 +        l16 * 32 + quad * 8);
            bf16x8 va1 = *(const bf16x8*)(Vb + g * 2048 + 512  + l16 * 32 + quad * 8);
            bf16x8 va2 = *(const bf16x8*)(Vb + g * 2048 + 1024 + l16 * 32 + quad * 8);
            bf16x8 va3 = *(const bf16x8*)(Vb + g * 2048 + 1536 + l16 * 32 + quad * 8);
            bf16x8 pb[2];
#pragma unroll
            for (int qi = 0; qi < 2; ++qi) {
                f32x4 z0 = {0.f, 0.f, 0.f, 0.f};
                f32x4 z1 = {0.f, 0.f, 0.f, 0.f};
                z0 = __builtin_amdgcn_mfma_f32_16x16x32_bf16(ka00, qb[qi][0], z0, 0, 0, 0);
                z0 = __builtin_amdgcn_mfma_f32_16x16x32_bf16(ka01, qb[qi][1], z0, 0, 0, 0);
                z1 = __builtin_amdgcn_mfma_f32_16x16x32_bf16(ka10, qb[qi][0], z1, 0, 0, 0);
                z1 = __builtin_amdgcn_mfma_f32_16x16x32_bf16(ka11, qb[qi][1], z1, 0, 0, 0);
                u32 ue[8];
                float ls = 0.f;
#pragma unroll
                for (int j = 0; j < 4; ++j) {
                    float e0 = __builtin_amdgcn_exp2f(z0[j]);
                    float e1 = __builtin_amdgcn_exp2f(z1[j]);
                    ls += e0 + e1;
                    union { float f; u32 v; } c0, c1;
                    c0.f = e0; c1.f = e1;
                    ue[j] = c0.v + 0x8000u;      // round-half-up to bf16
                    ue[4 + j] = c1.v + 0x8000u;
                }
                lsum[qi] += ls;
                union { uint4 u; bf16x8 b; } cv;
                cv.u.x = __builtin_amdgcn_perm(ue[1], ue[0], 0x07060302u);
                cv.u.y = __builtin_amdgcn_perm(ue[3], ue[2], 0x07060302u);
                cv.u.z = __builtin_amdgcn_perm(ue[5], ue[4], 0x07060302u);
                cv.u.w = __builtin_amdgcn_perm(ue[7], ue[6], 0x07060302u);
                pb[qi] = cv.b;
            }
            o[0][0] = __builtin_amdgcn_mfma_f32_16x16x32_bf16(va0, pb[0], o[0][0], 0, 0, 0);
            o[0][1] = __builtin_amdgcn_mfma_f32_16x16x32_bf16(va1, pb[0], o[0][1], 0, 0, 0);
            o[0][2] = __builtin_amdgcn_mfma_f32_16x16x32_bf16(va2, pb[0], o[0][2], 0, 0, 0);
            o[0][3] = __builtin_amdgcn_mfma_f32_16x16x32_bf16(va3, pb[0], o[0][3], 0, 0, 0);
            o[1][0] = __builtin_amdgcn_mfma_f32_16x16x32_bf16(va0, pb[1], o[1][0], 0, 0, 0);
            o[1][1] = __builtin_amdgcn_mfma_f32_16x16x32_bf16(va1, pb[1], o[1][1], 0, 0, 0);
            o[1][2] = __builtin_amdgcn_mfma_f32_16x16x32_bf16(va2, pb[1], o[1][2], 0, 0, 0);
            o[1][3] = __builtin_amdgcn_mfma_f32_16x16x32_bf16(va3, pb[1], o[1][3], 0, 0, 0);
        }
    }

    float rl[2];
#pragma unroll
    for (int qi = 0; qi < 2; ++qi) {
        float v = lsum[qi];
        v += __shfl_xor(v, 16, 64);
        v += __shfl_xor(v, 32, 64);
        rl[qi] = 1.0f / v;
    }
    __syncthreads();
    u16* Ksc = &KV[0][0];
#pragma unroll
    for (int qi = 0; qi < 2; ++qi)
#pragma unroll
        for (int dt = 0; dt < 4; ++dt)
#pragma unroll
            for (int jj = 0; jj < 2; ++jj) {
                u32 lo_ = (u32)f2bf(o[qi][dt][2 * jj] * rl[qi]);
                u32 hi_ = (u32)f2bf(o[qi][dt][2 * jj + 1] * rl[qi]);
                *(u32*)(Ksc + (w * 32 + qi * 16 + l16) * OST + dt * 16 + quad * 4 + jj * 2) =
                    lo_ | (hi_ << 16);
            }
    __syncthreads();
    const int b = bh >> 4, h = bh & 15;
#pragma unroll
    for (int i = 0; i < 4; ++i) {
        int idx = i * 256 + t;
        int q = idx >> 3, c = idx & 7;
        uint4 vv = *(const uint4*)(Ksc + q * OST + c * 8);
        *(uint4*)(AO + ((size_t)(b * SS + qt * 128 + q)) * EMBD + h * DH + c * 8) = vv;
    }
}

// ---------------- out projection GEMM: dbuf DMA pipeline, 1 barrier/iter ----
__global__ __launch_bounds__(256) void gemm_out(
    const u16* __restrict__ Ab,   // [4096][1024]
    const u16* __restrict__ Wb,   // [1024][1024]
    const float* __restrict__ b_out,
    float* __restrict__ Out)
{
    __shared__ u16 AB[2][8192];   // [buf][A 4096 | B 4096]  32 KB
    const int t = threadIdx.x;
    const int lane = t & 63;
    const int wave = t >> 6;
    const int wm = wave >> 1, wn = wave & 1;
    const int quad = lane >> 4, l16 = lane & 15;
    const int m0 = blockIdx.y * 128, n0 = blockIdx.x * 128;

    const int s0i = t, s1i = 256 + t;
    const u16* ga0 = Ab + (size_t)(m0 + (s0i >> 2)) * EMBD + (s0i & 3) * 8;
    const u16* ga1 = Ab + (size_t)(m0 + (s1i >> 2)) * EMBD + (s1i & 3) * 8;
    const u16* gb0 = Wb + (size_t)(n0 + (s0i >> 2)) * EMBD + (s0i & 3) * 8;
    const u16* gb1 = Wb + (size_t)(n0 + (s1i >> 2)) * EMBD + (s1i & 3) * 8;

    f32x4 acc[4][4] = {};

    {
        u16* buf = &AB[0][0];
        GLDS16(ga0, buf + s0i * 8);
        GLDS16(ga1, buf + s1i * 8);
        GLDS16(gb0, buf + 4096 + s0i * 8);
        GLDS16(gb1, buf + 4096 + s1i * 8);
    }

    for (int it = 0; it < EMBD / 32; ++it) {
        asm volatile("s_waitcnt vmcnt(0)" ::: "memory");
        __syncthreads();
        if (it + 1 < EMBD / 32) {
            int k0 = (it + 1) * 32;
            u16* buf = &AB[(it + 1) & 1][0];
            GLDS16(ga0 + k0, buf + s0i * 8);
            GLDS16(ga1 + k0, buf + s1i * 8);
            GLDS16(gb0 + k0, buf + 4096 + s0i * 8);
            GLDS16(gb1 + k0, buf + 4096 + s1i * 8);
        }
        const u16* As = &AB[it & 1][0];
        const u16* Bs = &AB[it & 1][4096];
        bf16x8 af[4], bfr[4];
#pragma unroll
        for (int im = 0; im < 4; ++im)
            af[im] = *(const bf16x8*)(As + (wm * 64 + im * 16 + l16) * 32 + quad * 8);
#pragma unroll
        for (int in = 0; in < 4; ++in)
            bfr[in] = *(const bf16x8*)(Bs + (wn * 64 + in * 16 + l16) * 32 + quad * 8);
#pragma unroll
        for (int im = 0; im < 4; ++im)
#pragma unroll
            for (int in = 0; in < 4; ++in)
                acc[im][in] = __builtin_amdgcn_mfma_f32_16x16x32_bf16(
                    af[im], bfr[in], acc[im][in], 0, 0, 0);
    }

#pragma unroll
    for (int im = 0; im < 4; ++im) {
        int rbase = m0 + wm * 64 + im * 16 + quad * 4;
#pragma unroll
        for (int in = 0; in < 4; ++in) {
            int col = n0 + wn * 64 + in * 16 + l16;
            float bias = b_out[col];
#pragma unroll
            for (int j = 0; j < 4; ++j)
                Out[(size_t)(rbase + j) * EMBD + col] = acc[im][in][j] + bias;
        }
    }
}

extern "C" void kernel_launch(void* const* d_in, const int* in_sizes, int n_in,
                              void* d_out, int out_size, void* d_ws, size_t ws_size,
                              hipStream_t stream)
{
    (void)in_sizes; (void)n_in; (void)out_size; (void)ws_size;
    const float* x     = (const float*)d_in[0];
    const float* W_in  = (const float*)d_in[1];
    const float* b_in  = (const float*)d_in[2];
    const float* W_out = (const float*)d_in[3];
    const float* b_out = (const float*)d_in[4];
    float* out = (float*)d_out;

    char* ws = (char*)d_ws;
    u16* xb  = (u16*)(ws);                          //  8 MB: x bf16 [4096][1024]
    u16* wib = (u16*)(ws + 8u  * 1024 * 1024);      //  6 MB: W_in bf16
    u16* wob = (u16*)(ws + 14u * 1024 * 1024);      //  2 MB: W_out bf16
    u16* Qw  = (u16*)(ws + 16u * 1024 * 1024);      //  8 MB: Q (x log2e/8)
    u16* Kw  = (u16*)(ws + 24u * 1024 * 1024);      //  8 MB: Kf fragment-linear
    u16* Vpw = (u16*)(ws + 32u * 1024 * 1024);      //  8 MB: Vpf frag-linear permuted
    u16* AO  = (u16*)(ws + 40u * 1024 * 1024);      //  8 MB: attn out bf16

    cast_all<<<(NX8 + NWI8 + NWO8) / 256, 256, 0, stream>>>(x, W_in, W_out, xb, wib, wob);
    gemm_qkv<<<dim3(N_QKV / 128, M_TOT / 128), 256, 0, stream>>>(xb, wib, b_in, Qw, Kw, Vpw);
    attn<<<512, 256, 0, stream>>>(Qw, Kw, Vpw, AO);
    gemm_out<<<dim3(EMBD / 128, M_TOT / 128), 256, 0, stream>>>(AO, wob, b_out, out);
}

// Round 10
// 178.842 us; speedup vs baseline: 1.0113x; 1.0113x over previous
//
#include <hip/hip_runtime.h>
#include <cstdint>

#define EMBD 1024
#define NH 16
#define DH 64
#define BB 2
#define SS 2048
#define M_TOT (BB*SS)     // 4096
#define N_QKV (3*EMBD)    // 3072

typedef __bf16 bf16_t;
typedef bf16_t bf16x8 __attribute__((ext_vector_type(8)));
typedef float f32x4 __attribute__((ext_vector_type(4)));
typedef unsigned short u16;
typedef unsigned int u32;

static __device__ __forceinline__ u16 f2bf(float f) {
    union { float f; unsigned u; } c; c.f = f;
    unsigned u = c.u;
    unsigned r = (u + 0x7FFFu + ((u >> 16) & 1u)) >> 16;  // RNE
    return (u16)r;
}

// async global->LDS, 16B per lane; LDS dest must be wave-uniform base + lane*16
#define GLDS16(gp, lp) \
    __builtin_amdgcn_global_load_lds((const __attribute__((address_space(1))) void*)(gp), \
                                     (__attribute__((address_space(3))) void*)(lp), 16, 0, 0)

// ---------------- fused cast fp32 -> bf16 for x, W_in, W_out ----------------
#define NX8 (M_TOT * EMBD / 8)          // 524288
#define NWI8 (N_QKV * EMBD / 8)         // 393216
#define NWO8 (EMBD * EMBD / 8)          // 131072
__global__ void cast_all(const float* __restrict__ x, const float* __restrict__ wi,
                         const float* __restrict__ wo, u16* __restrict__ xb,
                         u16* __restrict__ wib, u16* __restrict__ wob) {
    int i = blockIdx.x * blockDim.x + threadIdx.x;
    const float* s; u16* d; int off;
    if (i < NX8)              { s = x;  d = xb;  off = i; }
    else if (i < NX8 + NWI8)  { s = wi; d = wib; off = i - NX8; }
    else                      { s = wo; d = wob; off = i - NX8 - NWI8; }
    const float4* s4 = (const float4*)s;
    float4 a = s4[2 * off];
    float4 b = s4[2 * off + 1];
    union { u16 u[8]; uint4 v; } r;
    r.u[0] = f2bf(a.x); r.u[1] = f2bf(a.y); r.u[2] = f2bf(a.z); r.u[3] = f2bf(a.w);
    r.u[4] = f2bf(b.x); r.u[5] = f2bf(b.y); r.u[6] = f2bf(b.z); r.u[7] = f2bf(b.w);
    ((uint4*)d)[off] = r.v;
}

// ---------------- QKV GEMM: ring-3 DMA pipeline, vmcnt(4) deep drain --------
// C[i][o] = sum_d x[i][d]*W_in[o][d] + b_in[o]
// Epilogue layouts:
//   Q  [B,H,S,64] row-major, scaled by 0.125*log2(e)
//   Kf fragment-linear: per head, per 16-key tile (1024 u16):
//        off = tile*1024 + (d>>5)*512 + (key&15)*32 + ((d>>3)&3)*8 + (d&7)
//   Vpf fragment-linear, keys permuted per 32-block (2048 u16/group):
//        p = ((s>>2)&3)*8 + ((s>>4)&1)*4 + (s&3)
//        off = (s>>5)*2048 + (d>>4)*512 + (d&15)*32 + p
#define QSCALE (0.125f * 1.4426950408889634f)
__global__ __launch_bounds__(256) void gemm_qkv(
    const u16* __restrict__ Xb,   // [4096][1024]
    const u16* __restrict__ Wb,   // [3072][1024]
    const float* __restrict__ b_in,
    u16* __restrict__ Q, u16* __restrict__ Kf, u16* __restrict__ Vpf)
{
    __shared__ u16 AB[3][8192];   // [buf][A 4096 | B 4096]  48 KB (3 blocks/CU)
    const int t = threadIdx.x;
    const int lane = t & 63;
    const int wave = t >> 6;
    const int wm = wave >> 1, wn = wave & 1;
    const int quad = lane >> 4, l16 = lane & 15;
    const int m0 = blockIdx.y * 128, n0 = blockIdx.x * 128;

    const int s0i = t, s1i = 256 + t;
    const u16* ga0 = Xb + (size_t)(m0 + (s0i >> 2)) * EMBD + (s0i & 3) * 8;
    const u16* ga1 = Xb + (size_t)(m0 + (s1i >> 2)) * EMBD + (s1i & 3) * 8;
    const u16* gb0 = Wb + (size_t)(n0 + (s0i >> 2)) * EMBD + (s0i & 3) * 8;
    const u16* gb1 = Wb + (size_t)(n0 + (s1i >> 2)) * EMBD + (s1i & 3) * 8;

    f32x4 acc[4][4] = {};

    // prologue: DMA k-tiles 0 and 1 into bufs 0,1
#pragma unroll
    for (int p = 0; p < 2; ++p) {
        u16* buf = &AB[p][0];
        GLDS16(ga0 + p * 32, buf + s0i * 8);
        GLDS16(ga1 + p * 32, buf + s1i * 8);
        GLDS16(gb0 + p * 32, buf + 4096 + s0i * 8);
        GLDS16(gb1 + p * 32, buf + 4096 + s1i * 8);
    }

    int bi = 0;                    // buffer index = it % 3
    int bw = 2;                    // buffer index for it+2
    for (int it = 0; it < EMBD / 32; ++it) {
        // tile `it` was issued 2 compute-phases ago; only the 4 DMAs of tile
        // it+1 may remain outstanding -> fine-grained wait (never drain to 0)
        asm volatile("s_waitcnt vmcnt(4)" ::: "memory");
        __syncthreads();
        {   // always-issue tile it+2 (trailing OOB prefetches are benign:
            // reads land inside ws, writes go to bufs never read again)
            int k0 = (it + 2) * 32;
            u16* buf = &AB[bw][0];
            GLDS16(ga0 + k0, buf + s0i * 8);
            GLDS16(ga1 + k0, buf + s1i * 8);
            GLDS16(gb0 + k0, buf + 4096 + s0i * 8);
            GLDS16(gb1 + k0, buf + 4096 + s1i * 8);
        }
        const u16* As = &AB[bi][0];
        const u16* Bs = &AB[bi][4096];
        bf16x8 af[4], bfr[4];
#pragma unroll
        for (int im = 0; im < 4; ++im)
            af[im] = *(const bf16x8*)(As + (wm * 64 + im * 16 + l16) * 32 + quad * 8);
#pragma unroll
        for (int in = 0; in < 4; ++in)
            bfr[in] = *(const bf16x8*)(Bs + (wn * 64 + in * 16 + l16) * 32 + quad * 8);
#pragma unroll
        for (int im = 0; im < 4; ++im)
#pragma unroll
            for (int in = 0; in < 4; ++in)
                acc[im][in] = __builtin_amdgcn_mfma_f32_16x16x32_bf16(
                    af[im], bfr[in], acc[im][in], 0, 0, 0);
        bi = (bi == 2) ? 0 : bi + 1;
        bw = (bw == 2) ? 0 : bw + 1;
    }

    // epilogue: C/D layout col=lane&15, row=quad*4+reg
#pragma unroll
    for (int im = 0; im < 4; ++im) {
        int rbase = m0 + wm * 64 + im * 16 + quad * 4;
        int b = rbase >> 11, ss = rbase & (SS - 1);     // ss%4==0, keys ss..ss+3
#pragma unroll
        for (int in = 0; in < 4; ++in) {
            int col = n0 + wn * 64 + in * 16 + l16;
            float bias = b_in[col];
            float v0 = acc[im][in][0] + bias;
            float v1 = acc[im][in][1] + bias;
            float v2 = acc[im][in][2] + bias;
            float v3 = acc[im][in][3] + bias;
            if (col < EMBD) {
                int h = col >> 6, d = col & 63;
                u16* qp = Q + (((size_t)(b * NH + h) * SS) + ss) * DH + d;
                qp[0]      = f2bf(v0 * QSCALE);
                qp[DH]     = f2bf(v1 * QSCALE);
                qp[2 * DH] = f2bf(v2 * QSCALE);
                qp[3 * DH] = f2bf(v3 * QSCALE);
            } else if (col < 2 * EMBD) {
                int c = col - EMBD; int h = c >> 6, d = c & 63;
                u16* kp = Kf + (size_t)(b * NH + h) * SS * DH
                          + (ss >> 4) * 1024 + (d >> 5) * 512
                          + (ss & 15) * 32 + ((d >> 3) & 3) * 8 + (d & 7);
                kp[0]  = f2bf(v0);
                kp[32] = f2bf(v1);
                kp[64] = f2bf(v2);
                kp[96] = f2bf(v3);
            } else {
                int c = col - 2 * EMBD; int h = c >> 6, d = c & 63;
                int p32 = ((ss >> 2) & 3) * 8 + ((ss >> 4) & 1) * 4;  // + j for key ss+j
                u32 lo = (u32)f2bf(v0) | ((u32)f2bf(v1) << 16);
                u32 hi = (u32)f2bf(v2) | ((u32)f2bf(v3) << 16);
                uint2 pk; pk.x = lo; pk.y = hi;
                *(uint2*)(Vpf + (size_t)(b * NH + h) * SS * DH
                          + (ss >> 5) * 2048 + (d >> 4) * 512 + (d & 15) * 32 + p32) = pk;
            }
        }
    }
}

// ---------------- attention v8: 128-key tiles, dbuf DMA, 16 barriers total --
#define OST 72
__global__ __launch_bounds__(256, 2) void attn(
    const u16* __restrict__ Q, const u16* __restrict__ Kf,
    const u16* __restrict__ Vpf, u16* __restrict__ AO)
{
    __shared__ u16 KV[2][16384];    // [buf][K 8192 | V 8192]  64 KB
    const int t = threadIdx.x;
    const int lane = t & 63, w = t >> 6;
    const int quad = lane >> 4, l16 = lane & 15;
    const int b0 = blockIdx.x;
    const int bh = (b0 & 7) * 4 + ((b0 >> 3) & 3);   // XCD-clustered heads
    const int qt = b0 >> 5;
    const int q0 = qt * 128 + w * 32;

    const u16* Qh = Q + ((size_t)bh * SS + q0) * DH;
    const u16* Kh = Kf + (size_t)bh * SS * DH;     // chunk it: + it*8192
    const u16* Vh = Vpf + (size_t)bh * SS * DH;    // chunk it: + it*8192

    bf16x8 qb[2][2];
#pragma unroll
    for (int qi = 0; qi < 2; ++qi) {
        qb[qi][0] = *(const bf16x8*)(Qh + (qi * 16 + l16) * DH + quad * 8);
        qb[qi][1] = *(const bf16x8*)(Qh + (qi * 16 + l16) * DH + 32 + quad * 8);
    }

    f32x4 o[2][4] = {};
    float lsum[2] = {0.f, 0.f};

    // prefetch chunk 0 (128 keys: 16 KB K + 16 KB V) into buf 0
#pragma unroll
    for (int i = 0; i < 4; ++i) {
        GLDS16(Kh + i * 2048 + t * 8, &KV[0][0] + i * 2048 + t * 8);
        GLDS16(Vh + i * 2048 + t * 8, &KV[0][8192] + i * 2048 + t * 8);
    }

    for (int it = 0; it < SS / 128; ++it) {
        asm volatile("s_waitcnt vmcnt(0)" ::: "memory");
        __syncthreads();
        if (it + 1 < SS / 128) {
            const u16* kc = Kh + (it + 1) * 8192;
            const u16* vc = Vh + (it + 1) * 8192;
            u16* kb = &KV[(it + 1) & 1][0];
            u16* vb = &KV[(it + 1) & 1][8192];
#pragma unroll
            for (int i = 0; i < 4; ++i) {
                GLDS16(kc + i * 2048 + t * 8, kb + i * 2048 + t * 8);
                GLDS16(vc + i * 2048 + t * 8, vb + i * 2048 + t * 8);
            }
        }
        const u16* Kb = &KV[it & 1][0];
        const u16* Vb = &KV[it & 1][8192];
#pragma unroll
        for (int g = 0; g < 4; ++g) {    // 4 groups of 32 keys
            bf16x8 ka00 = *(const bf16x8*)(Kb + (2 * g) * 1024 +       l16 * 32 + quad * 8);
            bf16x8 ka01 = *(const bf16x8*)(Kb + (2 * g) * 1024 + 512 + l16 * 32 + quad * 8);
            bf16x8 ka10 = *(const bf16x8*)(Kb + (2 * g + 1) * 1024 +       l16 * 32 + quad * 8);
            bf16x8 ka11 = *(const bf16x8*)(Kb + (2 * g + 1) * 1024 + 512 + l16 * 32 + quad * 8);
            bf16x8 va0 = *(const bf16x8*)(Vb + g * 2048 +        l16 * 32 + quad * 8);
            bf16x8 va1 = *(const bf16x8*)(Vb + g * 2048 + 512  + l16 * 32 + quad * 8);
            bf16x8 va2 = *(const bf16x8*)(Vb + g * 2048 + 1024 + l16 * 32 + quad * 8);
            bf16x8 va3 = *(const bf16x8*)(Vb + g * 2048 + 1536 + l16 * 32 + quad * 8);
            bf16x8 pb[2];
#pragma unroll
            for (int qi = 0; qi < 2; ++qi) {
                f32x4 z0 = {0.f, 0.f, 0.f, 0.f};
                f32x4 z1 = {0.f, 0.f, 0.f, 0.f};
                z0 = __builtin_amdgcn_mfma_f32_16x16x32_bf16(ka00, qb[qi][0], z0, 0, 0, 0);
                z0 = __builtin_amdgcn_mfma_f32_16x16x32_bf16(ka01, qb[qi][1], z0, 0, 0, 0);
                z1 = __builtin_amdgcn_mfma_f32_16x16x32_bf16(ka10, qb[qi][0], z1, 0, 0, 0);
                z1 = __builtin_amdgcn_mfma_f32_16x16x32_bf16(ka11, qb[qi][1], z1, 0, 0, 0);
                u32 ue[8];
                float ls = 0.f;
#pragma unroll
                for (int j = 0; j < 4; ++j) {
                    float e0 = __builtin_amdgcn_exp2f(z0[j]);
                    float e1 = __builtin_amdgcn_exp2f(z1[j]);
                    ls += e0 + e1;
                    union { float f; u32 v; } c0, c1;
                    c0.f = e0; c1.f = e1;
                    ue[j] = c0.v + 0x8000u;      // round-half-up to bf16
                    ue[4 + j] = c1.v + 0x8000u;
                }
                lsum[qi] += ls;
                union { uint4 u; bf16x8 b; } cv;
                cv.u.x = __builtin_amdgcn_perm(ue[1], ue[0], 0x07060302u);
                cv.u.y = __builtin_amdgcn_perm(ue[3], ue[2], 0x07060302u);
                cv.u.z = __builtin_amdgcn_perm(ue[5], ue[4], 0x07060302u);
                cv.u.w = __builtin_amdgcn_perm(ue[7], ue[6], 0x07060302u);
                pb[qi] = cv.b;
            }
            o[0][0] = __builtin_amdgcn_mfma_f32_16x16x32_bf16(va0, pb[0], o[0][0], 0, 0, 0);
            o[0][1] = __builtin_amdgcn_mfma_f32_16x16x32_bf16(va1, pb[0], o[0][1], 0, 0, 0);
            o[0][2] = __builtin_amdgcn_mfma_f32_16x16x32_bf16(va2, pb[0], o[0][2], 0, 0, 0);
            o[0][3] = __builtin_amdgcn_mfma_f32_16x16x32_bf16(va3, pb[0], o[0][3], 0, 0, 0);
            o[1][0] = __builtin_amdgcn_mfma_f32_16x16x32_bf16(va0, pb[1], o[1][0], 0, 0, 0);
            o[1][1] = __builtin_amdgcn_mfma_f32_16x16x32_bf16(va1, pb[1], o[1][1], 0, 0, 0);
            o[1][2] = __builtin_amdgcn_mfma_f32_16x16x32_bf16(va2, pb[1], o[1][2], 0, 0, 0);
            o[1][3] = __builtin_amdgcn_mfma_f32_16x16x32_bf16(va3, pb[1], o[1][3], 0, 0, 0);
        }
    }

    float rl[2];
#pragma unroll
    for (int qi = 0; qi < 2; ++qi) {
        float v = lsum[qi];
        v += __shfl_xor(v, 16, 64);
        v += __shfl_xor(v, 32, 64);
        rl[qi] = 1.0f / v;
    }
    __syncthreads();
    u16* Ksc = &KV[0][0];
#pragma unroll
    for (int qi = 0; qi < 2; ++qi)
#pragma unroll
        for (int dt = 0; dt < 4; ++dt)
#pragma unroll
            for (int jj = 0; jj < 2; ++jj) {
                u32 lo_ = (u32)f2bf(o[qi][dt][2 * jj] * rl[qi]);
                u32 hi_ = (u32)f2bf(o[qi][dt][2 * jj + 1] * rl[qi]);
                *(u32*)(Ksc + (w * 32 + qi * 16 + l16) * OST + dt * 16 + quad * 4 + jj * 2) =
                    lo_ | (hi_ << 16);
            }
    __syncthreads();
    const int b = bh >> 4, h = bh & 15;
#pragma unroll
    for (int i = 0; i < 4; ++i) {
        int idx = i * 256 + t;
        int q = idx >> 3, c = idx & 7;
        uint4 vv = *(const uint4*)(Ksc + q * OST + c * 8);
        *(uint4*)(AO + ((size_t)(b * SS + qt * 128 + q)) * EMBD + h * DH + c * 8) = vv;
    }
}

// ---------------- out projection GEMM: ring-3 DMA pipeline, vmcnt(4) --------
__global__ __launch_bounds__(256) void gemm_out(
    const u16* __restrict__ Ab,   // [4096][1024]
    const u16* __restrict__ Wb,   // [1024][1024]
    const float* __restrict__ b_out,
    float* __restrict__ Out)
{
    __shared__ u16 AB[3][8192];   // [buf][A 4096 | B 4096]  48 KB
    const int t = threadIdx.x;
    const int lane = t & 63;
    const int wave = t >> 6;
    const int wm = wave >> 1, wn = wave & 1;
    const int quad = lane >> 4, l16 = lane & 15;
    const int m0 = blockIdx.y * 128, n0 = blockIdx.x * 128;

    const int s0i = t, s1i = 256 + t;
    const u16* ga0 = Ab + (size_t)(m0 + (s0i >> 2)) * EMBD + (s0i & 3) * 8;
    const u16* ga1 = Ab + (size_t)(m0 + (s1i >> 2)) * EMBD + (s1i & 3) * 8;
    const u16* gb0 = Wb + (size_t)(n0 + (s0i >> 2)) * EMBD + (s0i & 3) * 8;
    const u16* gb1 = Wb + (size_t)(n0 + (s1i >> 2)) * EMBD + (s1i & 3) * 8;

    f32x4 acc[4][4] = {};

#pragma unroll
    for (int p = 0; p < 2; ++p) {
        u16* buf = &AB[p][0];
        GLDS16(ga0 + p * 32, buf + s0i * 8);
        GLDS16(ga1 + p * 32, buf + s1i * 8);
        GLDS16(gb0 + p * 32, buf + 4096 + s0i * 8);
        GLDS16(gb1 + p * 32, buf + 4096 + s1i * 8);
    }

    int bi = 0, bw = 2;
    for (int it = 0; it < EMBD / 32; ++it) {
        asm volatile("s_waitcnt vmcnt(4)" ::: "memory");
        __syncthreads();
        {
            int k0 = (it + 2) * 32;
            u16* buf = &AB[bw][0];
            GLDS16(ga0 + k0, buf + s0i * 8);
            GLDS16(ga1 + k0, buf + s1i * 8);
            GLDS16(gb0 + k0, buf + 4096 + s0i * 8);
            GLDS16(gb1 + k0, buf + 4096 + s1i * 8);
        }
        const u16* As = &AB[bi][0];
        const u16* Bs = &AB[bi][4096];
        bf16x8 af[4], bfr[4];
#pragma unroll
        for (int im = 0; im < 4; ++im)
            af[im] = *(const bf16x8*)(As + (wm * 64 + im * 16 + l16) * 32 + quad * 8);
#pragma unroll
        for (int in = 0; in < 4; ++in)
            bfr[in] = *(const bf16x8*)(Bs + (wn * 64 + in * 16 + l16) * 32 + quad * 8);
#pragma unroll
        for (int im = 0; im < 4; ++im)
#pragma unroll
            for (int in = 0; in < 4; ++in)
                acc[im][in] = __builtin_amdgcn_mfma_f32_16x16x32_bf16(
                    af[im], bfr[in], acc[im][in], 0, 0, 0);
        bi = (bi == 2) ? 0 : bi + 1;
        bw = (bw == 2) ? 0 : bw + 1;
    }

#pragma unroll
    for (int im = 0; im < 4; ++im) {
        int rbase = m0 + wm * 64 + im * 16 + quad * 4;
#pragma unroll
        for (int in = 0; in < 4; ++in) {
            int col = n0 + wn * 64 + in * 16 + l16;
            float bias = b_out[col];
#pragma unroll
            for (int j = 0; j < 4; ++j)
                Out[(size_t)(rbase + j) * EMBD + col] = acc[im][in][j] + bias;
        }
    }
}

extern "C" void kernel_launch(void* const* d_in, const int* in_sizes, int n_in,
                              void* d_out, int out_size, void* d_ws, size_t ws_size,
                              hipStream_t stream)
{
    (void)in_sizes; (void)n_in; (void)out_size; (void)ws_size;
    const float* x     = (const float*)d_in[0];
    const float* W_in  = (const float*)d_in[1];
    const float* b_in  = (const float*)d_in[2];
    const float* W_out = (const float*)d_in[3];
    const float* b_out = (const float*)d_in[4];
    float* out = (float*)d_out;

    char* ws = (char*)d_ws;
    u16* xb  = (u16*)(ws);                          //  8 MB: x bf16 [4096][1024]
    u16* wib = (u16*)(ws + 8u  * 1024 * 1024);      //  6 MB: W_in bf16
    u16* wob = (u16*)(ws + 14u * 1024 * 1024);      //  2 MB: W_out bf16
    u16* Qw  = (u16*)(ws + 16u * 1024 * 1024);      //  8 MB: Q (x log2e/8)
    u16* Kw  = (u16*)(ws + 24u * 1024 * 1024);      //  8 MB: Kf fragment-linear
    u16* Vpw = (u16*)(ws + 32u * 1024 * 1024);      //  8 MB: Vpf frag-linear permuted
    u16* AO  = (u16*)(ws + 40u * 1024 * 1024);      //  8 MB: attn out bf16

    cast_all<<<(NX8 + NWI8 + NWO8) / 256, 256, 0, stream>>>(x, W_in, W_out, xb, wib, wob);
    gemm_qkv<<<dim3(N_QKV / 128, M_TOT / 128), 256, 0, stream>>>(xb, wib, b_in, Qw, Kw, Vpw);
    attn<<<512, 256, 0, stream>>>(Qw, Kw, Vpw, AO);
    gemm_out<<<dim3(EMBD / 128, M_TOT / 128), 256, 0, stream>>>(AO, wob, b_out, out);
}